// Round 1
// baseline (272.970 us; speedup 1.0000x reference)
//
#include <hip/hip_runtime.h>

#define NB 32
#define NA 3
#define GD 52
#define GG 2704          // 52*52
#define NC 80
#define CHN 85           // NC + 5
#define TILE 104         // spatial cells per block (divides 2704)
#define NT4 26           // TILE/4
#define PAD 107          // TILE + 3, odd & coprime with 32 -> conflict-free transpose reads
#define TPP 26           // tiles per (b,a) plane = 2704/104
#define EPSF 1e-12f

__device__ __forceinline__ float sigm(float v) { return 1.0f / (1.0f + __expf(-v)); }
__device__ __forceinline__ float bcef(float p, float t) {
    float pa = fminf(fmaxf(p, EPSF), 1.0f);
    float pb = fminf(fmaxf(1.0f - p, EPSF), 1.0f);
    return -(t * __logf(pa) + (1.0f - t) * __logf(pb));
}

__global__ __launch_bounds__(256) void yolo_main(
    const float* __restrict__ x,
    const float* __restrict__ tx, const float* __restrict__ ty,
    const float* __restrict__ tw, const float* __restrict__ th,
    const float* __restrict__ tconf, const float* __restrict__ tcls,
    const float* __restrict__ sw1,
    const int* __restrict__ om, const int* __restrict__ nm,
    const int* __restrict__ imgdim,
    float* __restrict__ out, double* __restrict__ acc)
{
    __shared__ float lx[CHN * PAD];      // transposed/transformed tile: [ch][s]
    __shared__ float laux[8][TILE];      // tx,ty,tw,th,tconf,sw,om,nm
    __shared__ float lred[4][9];

    const int tid   = threadIdx.x;
    const int bid   = blockIdx.x;
    const int tile  = bid % TPP;
    const int plane = bid / TPP;
    const int a     = plane % NA;
    const int b     = plane / NA;
    const int s0    = tile * TILE;

    // img_dim may arrive as int32 or float32 bits; handle both. stride = img/52.
    int iv = imgdim[0];
    float imgf = (iv > 0 && iv < 65536) ? (float)iv : __int_as_float(iv);
    const float stride = imgf / (float)GD;
    // output w/h = exp(pw) * (anchor/stride) * stride = exp(pw) * anchor
    const float aw = (a == 0) ? 10.0f : ((a == 1) ? 16.0f : 33.0f);
    const float ah = (a == 0) ? 13.0f : ((a == 1) ? 30.0f : 23.0f);

    const long paux = (long)((b * NA + a) * GG + s0);

    float nobj_p = 0.0f, nnob_p = 0.0f;
    if (tid < TILE) {
        float vtx = tx[paux + tid],    vty = ty[paux + tid];
        float vtw = tw[paux + tid],    vth = th[paux + tid];
        float vtc = tconf[paux + tid], vsw = sw1[paux + tid];
        float vom = (float)om[paux + tid], vnm = (float)nm[paux + tid];
        laux[0][tid] = vtx; laux[1][tid] = vty; laux[2][tid] = vtw; laux[3][tid] = vth;
        laux[4][tid] = vtc; laux[5][tid] = vsw; laux[6][tid] = vom; laux[7][tid] = vnm;
        nobj_p = vom; nnob_p = vnm;
    }
    __syncthreads();

    float s_x = 0.f, s_y = 0.f, s_w = 0.f, s_h = 0.f, s_co = 0.f, s_cn = 0.f, s_cl = 0.f;

    const float* xb = x + (long)(b * (NA * CHN) + a * CHN) * GG + s0;

    // Phase 2: coalesced float4 loads of x, transform per channel, store to LDS.
    for (int i4 = tid; i4 < CHN * NT4; i4 += 256) {
        int ch = i4 / NT4;
        int sq = (i4 - ch * NT4) * 4;
        float4 v4 = *(const float4*)(xb + (long)ch * GG + sq);
        float vv[4] = { v4.x, v4.y, v4.z, v4.w };
        float oo[4];
        if (ch >= 5) {
            #pragma unroll
            for (int j = 0; j < 4; ++j) oo[j] = sigm(vv[j]);
        } else if (ch == 0) {
            #pragma unroll
            for (int j = 0; j < 4; ++j) {
                int s = sq + j;
                int gx = (s0 + s) % GD;
                float p = sigm(vv[j]);
                float d = p - laux[0][s];
                s_x = fmaf(laux[6][s] * laux[5][s], d * d, s_x);
                oo[j] = (p + (float)gx) * stride;
            }
        } else if (ch == 1) {
            #pragma unroll
            for (int j = 0; j < 4; ++j) {
                int s = sq + j;
                int gy = (s0 + s) / GD;
                float p = sigm(vv[j]);
                float d = p - laux[1][s];
                s_y = fmaf(laux[6][s] * laux[5][s], d * d, s_y);
                oo[j] = (p + (float)gy) * stride;
            }
        } else if (ch == 2) {
            #pragma unroll
            for (int j = 0; j < 4; ++j) {
                int s = sq + j;
                float d = vv[j] - laux[2][s];
                s_w = fmaf(laux[6][s] * laux[5][s], d * d, s_w);
                oo[j] = __expf(vv[j]) * aw;
            }
        } else if (ch == 3) {
            #pragma unroll
            for (int j = 0; j < 4; ++j) {
                int s = sq + j;
                float d = vv[j] - laux[3][s];
                s_h = fmaf(laux[6][s] * laux[5][s], d * d, s_h);
                oo[j] = __expf(vv[j]) * ah;
            }
        } else { // ch == 4
            #pragma unroll
            for (int j = 0; j < 4; ++j) {
                int s = sq + j;
                float p = sigm(vv[j]);
                float bb = bcef(p, laux[4][s]);
                s_co = fmaf(laux[6][s] * laux[5][s], bb, s_co);
                s_cn = fmaf(laux[7][s], bb, s_cn);
                oo[j] = p;
            }
        }
        #pragma unroll
        for (int j = 0; j < 4; ++j) lx[ch * PAD + sq + j] = oo[j];
    }
    __syncthreads();

    // Phase 3: coalesced float4 output writes; transposed LDS reads.
    float* ob = out + (long)((b * NA + a) * GG + s0) * CHN;
    for (int i4 = tid; i4 < (TILE * CHN) / 4; i4 += 256) {
        int idx = i4 * 4;
        int s = idx / CHN;
        int c = idx - s * CHN;
        float w[4];
        #pragma unroll
        for (int j = 0; j < 4; ++j) {
            int cc = c + j, ss = s;
            if (cc >= CHN) { cc -= CHN; ss += 1; }
            w[j] = lx[cc * PAD + ss];
        }
        *(float4*)(ob + idx) = make_float4(w[0], w[1], w[2], w[3]);
    }

    // Phase 4: cls BCE, coalesced over tcls layout; skip HBM reads where om==0.
    const float* tb = tcls + (long)((b * NA + a) * GG + s0) * NC;
    for (int i4 = tid; i4 < (TILE * NC) / 4; i4 += 256) {
        int idx = i4 * 4;
        int s = idx / NC;
        int c = idx - s * NC;   // multiple of 4, never crosses s
        float oms = laux[6][s];
        if (oms != 0.0f) {
            float4 t4 = *(const float4*)(tb + idx);
            float tt[4] = { t4.x, t4.y, t4.z, t4.w };
            #pragma unroll
            for (int j = 0; j < 4; ++j) {
                float p = lx[(5 + c + j) * PAD + s];
                s_cl += bcef(p, tt[j]);
            }
        }
    }

    // Phase 5: block reduction of the 9 partials -> double atomics.
    float vals[9] = { nobj_p, nnob_p, s_x, s_y, s_w, s_h, s_co, s_cn, s_cl };
    #pragma unroll
    for (int k = 0; k < 9; ++k) {
        float v = vals[k];
        #pragma unroll
        for (int off = 32; off > 0; off >>= 1) v += __shfl_down(v, off, 64);
        vals[k] = v;
    }
    const int wv = tid >> 6, ln = tid & 63;
    if (ln == 0) {
        #pragma unroll
        for (int k = 0; k < 9; ++k) lred[wv][k] = vals[k];
    }
    __syncthreads();
    if (tid == 0) {
        #pragma unroll
        for (int k = 0; k < 9; ++k) {
            float s = lred[0][k] + lred[1][k] + lred[2][k] + lred[3][k];
            atomicAdd(&acc[k], (double)s);
        }
    }
}

__global__ void yolo_final(const double* __restrict__ acc, float* __restrict__ out_loss)
{
    double nobj   = fmax(acc[0], 1.0);
    double nnoobj = fmax(acc[1], 1.0);
    double total = (acc[2] + acc[3] + acc[4] + acc[5]) / nobj     // x,y,w,h
                 + acc[6] / nobj + 100.0 * acc[7] / nnoobj        // conf
                 + acc[8] / (nobj * (double)NC);                  // cls
    *out_loss = (float)total;
}

extern "C" void kernel_launch(void* const* d_in, const int* in_sizes, int n_in,
                              void* d_out, int out_size, void* d_ws, size_t ws_size,
                              hipStream_t stream)
{
    const float* x     = (const float*)d_in[0];
    const float* tx    = (const float*)d_in[1];
    const float* ty    = (const float*)d_in[2];
    const float* tw    = (const float*)d_in[3];
    const float* th    = (const float*)d_in[4];
    const float* tconf = (const float*)d_in[5];
    const float* tcls  = (const float*)d_in[6];
    const float* sw1   = (const float*)d_in[7];
    const int*   om    = (const int*)d_in[8];
    const int*   nm    = (const int*)d_in[9];
    const int*   img   = (const int*)d_in[10];
    float* out  = (float*)d_out;
    double* acc = (double*)d_ws;

    hipMemsetAsync(d_ws, 0, 9 * sizeof(double), stream);

    dim3 grid(NB * NA * TPP);   // 32*3*26 = 2496 blocks
    yolo_main<<<grid, 256, 0, stream>>>(x, tx, ty, tw, th, tconf, tcls, sw1,
                                        om, nm, img, out, acc);
    yolo_final<<<1, 1, 0, stream>>>(acc, out + (out_size - 1));
}

// Round 2
// 80.599 us; speedup vs baseline: 3.3868x; 3.3868x over previous
//
#include <hip/hip_runtime.h>

#define NB 32
#define NA 3
#define GD 52
#define GG 2704          // 52*52
#define NC 80
#define CHN 85           // NC + 5
#define TILE 52          // one grid row per block
#define NT4 13           // TILE/4
#define PAD 55           // lx leading-dim pad
#define TPP 52           // tiles per (b,a) plane = 2704/52
#define NBLK (NB * NA * TPP)   // 4992
#define NPAD 5120        // padded per-plane stride in ws (floats)
#define EPSF 1e-12f

__device__ __forceinline__ float sigm(float v) { return 1.0f / (1.0f + __expf(-v)); }
__device__ __forceinline__ float bcef(float p, float t) {
    float pa = fminf(fmaxf(p, EPSF), 1.0f);
    float pb = fminf(fmaxf(1.0f - p, EPSF), 1.0f);
    return -(t * __logf(pa) + (1.0f - t) * __logf(pb));
}

__global__ __launch_bounds__(256) void yolo_main(
    const float* __restrict__ x,
    const float* __restrict__ tx, const float* __restrict__ ty,
    const float* __restrict__ tw, const float* __restrict__ th,
    const float* __restrict__ tconf, const float* __restrict__ tcls,
    const float* __restrict__ sw1,
    const int* __restrict__ om, const int* __restrict__ nm,
    const int* __restrict__ imgdim,
    float* __restrict__ out,
    float* __restrict__ partials,      // [9][NPAD] plane-major; may be null
    double* __restrict__ accD)         // fallback padded atomics (stride 8 doubles)
{
    __shared__ float lx[CHN * PAD];    // transposed/transformed tile: [ch][s]
    __shared__ float laux[8][TILE];    // tx,ty,tw,th,tconf,sw,om,nm
    __shared__ float lred[4][9];

    const int tid   = threadIdx.x;
    const int bid   = blockIdx.x;
    const int tile  = bid % TPP;       // = grid row gy
    const int plane = bid / TPP;
    const int a     = plane % NA;
    const int b     = plane / NA;
    const int s0    = tile * TILE;

    int iv = imgdim[0];
    float imgf = (iv > 0 && iv < 65536) ? (float)iv : __int_as_float(iv);
    const float stride = imgf / (float)GD;
    const float aw = (a == 0) ? 10.0f : ((a == 1) ? 16.0f : 33.0f);
    const float ah = (a == 0) ? 13.0f : ((a == 1) ? 30.0f : 23.0f);
    const float gyf = (float)tile;     // gy constant per block; gx = s

    const long paux = (long)((b * NA + a) * GG + s0);

    float nobj_p = 0.0f, nnob_p = 0.0f;
    if (tid < TILE) {
        float vtx = tx[paux + tid],    vty = ty[paux + tid];
        float vtw = tw[paux + tid],    vth = th[paux + tid];
        float vtc = tconf[paux + tid], vsw = sw1[paux + tid];
        float vom = (float)om[paux + tid], vnm = (float)nm[paux + tid];
        laux[0][tid] = vtx; laux[1][tid] = vty; laux[2][tid] = vtw; laux[3][tid] = vth;
        laux[4][tid] = vtc; laux[5][tid] = vsw; laux[6][tid] = vom; laux[7][tid] = vnm;
        nobj_p = vom; nnob_p = vnm;
    }
    __syncthreads();

    float s_x = 0.f, s_y = 0.f, s_w = 0.f, s_h = 0.f, s_co = 0.f, s_cn = 0.f, s_cl = 0.f;

    const float* xb = x + (long)(b * (NA * CHN) + a * CHN) * GG + s0;

    // Phase 2: coalesced float4 loads of x, transform per channel, store to LDS.
    for (int i4 = tid; i4 < CHN * NT4; i4 += 256) {
        int ch = i4 / NT4;
        int sq = (i4 - ch * NT4) * 4;
        float4 v4 = *(const float4*)(xb + (long)ch * GG + sq);
        float vv[4] = { v4.x, v4.y, v4.z, v4.w };
        float oo[4];
        if (ch >= 5) {
            #pragma unroll
            for (int j = 0; j < 4; ++j) oo[j] = sigm(vv[j]);
        } else if (ch == 0) {
            #pragma unroll
            for (int j = 0; j < 4; ++j) {
                int s = sq + j;
                float p = sigm(vv[j]);
                float d = p - laux[0][s];
                s_x = fmaf(laux[6][s] * laux[5][s], d * d, s_x);
                oo[j] = (p + (float)s) * stride;      // gx = s
            }
        } else if (ch == 1) {
            #pragma unroll
            for (int j = 0; j < 4; ++j) {
                int s = sq + j;
                float p = sigm(vv[j]);
                float d = p - laux[1][s];
                s_y = fmaf(laux[6][s] * laux[5][s], d * d, s_y);
                oo[j] = (p + gyf) * stride;           // gy = tile
            }
        } else if (ch == 2) {
            #pragma unroll
            for (int j = 0; j < 4; ++j) {
                int s = sq + j;
                float d = vv[j] - laux[2][s];
                s_w = fmaf(laux[6][s] * laux[5][s], d * d, s_w);
                oo[j] = __expf(vv[j]) * aw;
            }
        } else if (ch == 3) {
            #pragma unroll
            for (int j = 0; j < 4; ++j) {
                int s = sq + j;
                float d = vv[j] - laux[3][s];
                s_h = fmaf(laux[6][s] * laux[5][s], d * d, s_h);
                oo[j] = __expf(vv[j]) * ah;
            }
        } else { // ch == 4
            #pragma unroll
            for (int j = 0; j < 4; ++j) {
                int s = sq + j;
                float p = sigm(vv[j]);
                float bb = bcef(p, laux[4][s]);
                s_co = fmaf(laux[6][s] * laux[5][s], bb, s_co);
                s_cn = fmaf(laux[7][s], bb, s_cn);
                oo[j] = p;
            }
        }
        #pragma unroll
        for (int j = 0; j < 4; ++j) lx[ch * PAD + sq + j] = oo[j];
    }
    __syncthreads();

    // Phase 3: coalesced float4 output writes; transposed LDS reads.
    float* ob = out + (long)((b * NA + a) * GG + s0) * CHN;
    for (int i4 = tid; i4 < (TILE * CHN) / 4; i4 += 256) {
        int idx = i4 * 4;
        int s = idx / CHN;
        int c = idx - s * CHN;
        float w[4];
        #pragma unroll
        for (int j = 0; j < 4; ++j) {
            int cc = c + j, ss = s;
            if (cc >= CHN) { cc -= CHN; ss += 1; }
            w[j] = lx[cc * PAD + ss];
        }
        *(float4*)(ob + idx) = make_float4(w[0], w[1], w[2], w[3]);
    }

    // Phase 4: cls BCE, coalesced over tcls layout; skip HBM reads where om==0.
    const float* tb = tcls + (long)((b * NA + a) * GG + s0) * NC;
    for (int i4 = tid; i4 < (TILE * NC) / 4; i4 += 256) {
        int idx = i4 * 4;
        int s = idx / NC;
        int c = idx - s * NC;   // multiple of 4, never crosses a cell
        float oms = laux[6][s];
        if (oms != 0.0f) {
            float4 t4 = *(const float4*)(tb + idx);
            float tt[4] = { t4.x, t4.y, t4.z, t4.w };
            #pragma unroll
            for (int j = 0; j < 4; ++j) {
                float p = lx[(5 + c + j) * PAD + s];
                s_cl += bcef(p, tt[j]);
            }
        }
    }

    // Phase 5: block reduction of the 9 partials -> one ws slot per block.
    float vals[9] = { nobj_p, nnob_p, s_x, s_y, s_w, s_h, s_co, s_cn, s_cl };
    #pragma unroll
    for (int k = 0; k < 9; ++k) {
        float v = vals[k];
        #pragma unroll
        for (int off = 32; off > 0; off >>= 1) v += __shfl_down(v, off, 64);
        vals[k] = v;
    }
    const int wv = tid >> 6, ln = tid & 63;
    if (ln == 0) {
        #pragma unroll
        for (int k = 0; k < 9; ++k) lred[wv][k] = vals[k];
    }
    __syncthreads();
    if (tid == 0) {
        if (partials) {
            #pragma unroll
            for (int k = 0; k < 9; ++k)
                partials[k * NPAD + bid] = lred[0][k] + lred[1][k] + lred[2][k] + lred[3][k];
        } else {
            #pragma unroll
            for (int k = 0; k < 9; ++k) {
                float s = lred[0][k] + lred[1][k] + lred[2][k] + lred[3][k];
                atomicAdd(&accD[k * 8], (double)s);   // 64B-padded fallback
            }
        }
    }
}

__device__ __forceinline__ void final_loss(const double* t, float* out_loss) {
    double nobj   = fmax(t[0], 1.0);
    double nnoobj = fmax(t[1], 1.0);
    double total = (t[2] + t[3] + t[4] + t[5]) / nobj
                 + t[6] / nobj + 100.0 * t[7] / nnoobj
                 + t[8] / (nobj * (double)NC);
    *out_loss = (float)total;
}

// One wave per plane (9 waves = 576 threads); double accumulation.
__global__ __launch_bounds__(576) void yolo_reduce(const float* __restrict__ partials,
                                                   float* __restrict__ out_loss)
{
    __shared__ double sred[9];
    const int w = threadIdx.x >> 6, ln = threadIdx.x & 63;
    if (w < 9) {
        double s = 0.0;
        for (int i = ln; i < NBLK; i += 64) s += (double)partials[w * NPAD + i];
        #pragma unroll
        for (int off = 32; off > 0; off >>= 1) s += __shfl_down(s, off, 64);
        if (ln == 0) sred[w] = s;
    }
    __syncthreads();
    if (threadIdx.x == 0) final_loss(sred, out_loss);
}

__global__ void yolo_final_atomic(const double* __restrict__ accD, float* __restrict__ out_loss)
{
    double t[9];
    #pragma unroll
    for (int k = 0; k < 9; ++k) t[k] = accD[k * 8];
    final_loss(t, out_loss);
}

extern "C" void kernel_launch(void* const* d_in, const int* in_sizes, int n_in,
                              void* d_out, int out_size, void* d_ws, size_t ws_size,
                              hipStream_t stream)
{
    const float* x     = (const float*)d_in[0];
    const float* tx    = (const float*)d_in[1];
    const float* ty    = (const float*)d_in[2];
    const float* tw    = (const float*)d_in[3];
    const float* th    = (const float*)d_in[4];
    const float* tconf = (const float*)d_in[5];
    const float* tcls  = (const float*)d_in[6];
    const float* sw1   = (const float*)d_in[7];
    const int*   om    = (const int*)d_in[8];
    const int*   nm    = (const int*)d_in[9];
    const int*   img   = (const int*)d_in[10];
    float* out = (float*)d_out;

    const size_t need = (size_t)9 * NPAD * sizeof(float);
    dim3 grid(NBLK);   // 32*3*52 = 4992 blocks

    if (ws_size >= need) {
        float* partials = (float*)d_ws;
        yolo_main<<<grid, 256, 0, stream>>>(x, tx, ty, tw, th, tconf, tcls, sw1,
                                            om, nm, img, out, partials, nullptr);
        yolo_reduce<<<1, 576, 0, stream>>>(partials, out + (out_size - 1));
    } else {
        double* accD = (double*)d_ws;
        hipMemsetAsync(d_ws, 0, 9 * 8 * sizeof(double), stream);
        yolo_main<<<grid, 256, 0, stream>>>(x, tx, ty, tw, th, tconf, tcls, sw1,
                                            om, nm, img, out, nullptr, accD);
        yolo_final_atomic<<<1, 1, 0, stream>>>(accD, out + (out_size - 1));
    }
}